// Round 7
// baseline (143.779 us; speedup 1.0000x reference)
//
#include <hip/hip_runtime.h>
#include <hip/hip_bf16.h>
#include <math.h>

#define L_SEQ 2048
#define DIMN  1024
#define NH    16
#define HD    64
#define NB    2
#define NTOK  (NB * L_SEQ)   // 4096

typedef __attribute__((ext_vector_type(8))) short bf16x8;
typedef __attribute__((ext_vector_type(4))) float f32x4;
typedef __attribute__((ext_vector_type(4))) short short4v;
typedef __attribute__((ext_vector_type(2))) unsigned uint32x2;

__device__ __forceinline__ short f2bf(float x) {
  return (short)__bfloat16_as_ushort(__float2bfloat16(x));
}

// v_cvt_pk_bf16_f32: low16 = bf16(lo), high16 = bf16(hi)
__device__ __forceinline__ unsigned cvt_pk_bf16(float lo, float hi) {
  unsigned r;
  asm("v_cvt_pk_bf16_f32 %0, %1, %2" : "=v"(r) : "v"(lo), "v"(hi));
  return r;
}

__device__ __forceinline__ void gload_lds16(const short* gsrc, char* lds_dst) {
  __builtin_amdgcn_global_load_lds(
      (const __attribute__((address_space(1))) void*)gsrc,
      (__attribute__((address_space(3))) void*)lds_dst, 16, 0, 0);
}

// ---------------------------------------------------------------------------
// cast x fp32 -> bf16, 8 elems/thread
// ---------------------------------------------------------------------------
__global__ __launch_bounds__(256) void cast_x_k(const float* __restrict__ in,
                                                short* __restrict__ out) {
  const int i = (blockIdx.x * 256 + threadIdx.x) * 8;
  float4 a = *(const float4*)(in + i);
  float4 b = *(const float4*)(in + i + 4);
  bf16x8 o;
  o[0] = f2bf(a.x); o[1] = f2bf(a.y); o[2] = f2bf(a.z); o[3] = f2bf(a.w);
  o[4] = f2bf(b.x); o[5] = f2bf(b.y); o[6] = f2bf(b.z); o[7] = f2bf(b.w);
  *(bf16x8*)(out + i) = o;
}

// ---------------------------------------------------------------------------
// transpose+cast: Wt[n][k] = bf16(W[k][n]), 64x64 LDS tiles
// ---------------------------------------------------------------------------
__global__ __launch_bounds__(256) void castT_k(const float* __restrict__ W,
                                               short* __restrict__ Wt) {
  __shared__ float s[64][65];
  const int tid = threadIdx.x;
  const int k0 = blockIdx.y * 64, n0 = blockIdx.x * 64;
#pragma unroll
  for (int i = 0; i < 4; ++i) {
    int idx = i * 256 + tid;
    int r = idx >> 4, c = (idx & 15) * 4;
    float4 v = *(const float4*)(W + (size_t)(k0 + r) * DIMN + n0 + c);
    s[r][c] = v.x; s[r][c + 1] = v.y; s[r][c + 2] = v.z; s[r][c + 3] = v.w;
  }
  __syncthreads();
#pragma unroll
  for (int i = 0; i < 4; ++i) {
    int idx = i * 256 + tid;
    int r = idx >> 4, c = (idx & 15) * 4;
    short4v o = { f2bf(s[c][r]), f2bf(s[c + 1][r]), f2bf(s[c + 2][r]), f2bf(s[c + 3][r]) };
    *(short4v*)(Wt + (size_t)(n0 + r) * DIMN + k0 + c) = o;
  }
}

// ---------------------------------------------------------------------------
// transpose V: [B,H,L,D] bf16 -> Vt [B,H,D,L] bf16. Grid (L/64, B*H).
// ---------------------------------------------------------------------------
__global__ __launch_bounds__(256) void vT_k(const short* __restrict__ V,
                                            short* __restrict__ Vt) {
  __shared__ short s[64][72];
  const int tid = threadIdx.x;
  const int bh = blockIdx.y;
  const int l0 = blockIdx.x * 64;
  const int row = tid >> 2, c0 = (tid & 3) * 16;
  const short* Vh = V + (size_t)bh * L_SEQ * HD;
  bf16x8 a = *(const bf16x8*)(Vh + (size_t)(l0 + row) * HD + c0);
  bf16x8 b = *(const bf16x8*)(Vh + (size_t)(l0 + row) * HD + c0 + 8);
#pragma unroll
  for (int j = 0; j < 8; ++j) { s[c0 + j][row] = a[j]; s[c0 + 8 + j][row] = b[j]; }
  __syncthreads();
  short* Vth = Vt + (size_t)bh * HD * L_SEQ;
  bf16x8 o0 = *(const bf16x8*)&s[row][c0];
  bf16x8 o1 = *(const bf16x8*)&s[row][c0 + 8];
  *(bf16x8*)(Vth + (size_t)row * L_SEQ + l0 + c0) = o0;
  *(bf16x8*)(Vth + (size_t)row * L_SEQ + l0 + c0 + 8) = o1;
}

// ---------------------------------------------------------------------------
// bf16 MFMA GEMM. MODE 0: bf16 [B,H,L,D] out, scale0 on z==0 (Q).
// MODE 1: fp32 out row-major.
// ---------------------------------------------------------------------------
template <int MODE>
__global__ __launch_bounds__(256) void mm_k(const short* __restrict__ A,
                                            const short* __restrict__ B0,
                                            const short* __restrict__ B1,
                                            const short* __restrict__ B2,
                                            void* __restrict__ C0,
                                            void* __restrict__ C1,
                                            void* __restrict__ C2,
                                            float scale0) {
  __shared__ char smem[65536];
  const int tid  = threadIdx.x;
  const int lane = tid & 63, wv = tid >> 6;
  const int g = lane >> 4, r16 = lane & 15;
  const int wr = wv >> 1, wc = wv & 1;
  const int row0 = blockIdx.y * 128, col0 = blockIdx.x * 128;
  const int z = blockIdx.z;
  const short* Bt = (z == 0) ? B0 : (z == 1 ? B1 : B2);
  const float scale = (MODE == 0 && z == 0) ? scale0 : 1.0f;

  f32x4 acc[4][4];
#pragma unroll
  for (int mi = 0; mi < 4; ++mi)
#pragma unroll
    for (int ni = 0; ni < 4; ++ni) acc[mi][ni] = (f32x4){0.f, 0.f, 0.f, 0.f};

  auto stage = [&](int buf, int kt) {
    const int k0 = kt * 64;
    char* As = smem + buf * 32768;
    char* Bs = As + 16384;
#pragma unroll
    for (int j = 0; j < 4; ++j) {
      const int o = j * 4096 + wv * 1024 + lane * 16;
      const int row = o >> 7;
      const int slot = (o >> 4) & 7;
      const int ksrc = k0 + ((slot ^ (row & 7)) << 3);
      gload_lds16(A  + (size_t)(row0 + row) * DIMN + ksrc, As + j * 4096 + wv * 1024);
      gload_lds16(Bt + (size_t)(col0 + row) * DIMN + ksrc, Bs + j * 4096 + wv * 1024);
    }
  };

  auto compute = [&](int buf) {
    const char* As = smem + buf * 32768;
    const char* Bs = As + 16384;
#pragma unroll
    for (int ks = 0; ks < 2; ++ks) {
      bf16x8 a[4], b[4];
#pragma unroll
      for (int mi = 0; mi < 4; ++mi) {
        const int row = wr * 64 + mi * 16 + r16;
        const int slot = (ks * 4 + g) ^ (row & 7);
        a[mi] = *(const bf16x8*)(As + row * 128 + slot * 16);
      }
#pragma unroll
      for (int ni = 0; ni < 4; ++ni) {
        const int row = wc * 64 + ni * 16 + r16;
        const int slot = (ks * 4 + g) ^ (row & 7);
        b[ni] = *(const bf16x8*)(Bs + row * 128 + slot * 16);
      }
#pragma unroll
      for (int mi = 0; mi < 4; ++mi)
#pragma unroll
        for (int ni = 0; ni < 4; ++ni)
          acc[mi][ni] = __builtin_amdgcn_mfma_f32_16x16x32_bf16(a[mi], b[ni], acc[mi][ni], 0, 0, 0);
    }
  };

  stage(0, 0);
  __syncthreads();
  int cur = 0;
  for (int kt = 0; kt < DIMN / 64 - 1; ++kt) {
    stage(cur ^ 1, kt + 1);
    compute(cur);
    __syncthreads();
    cur ^= 1;
  }
  compute(cur);

  void* Cp = (z == 0) ? C0 : (z == 1 ? C1 : C2);
#pragma unroll
  for (int mi = 0; mi < 4; ++mi) {
#pragma unroll
    for (int reg = 0; reg < 4; ++reg) {
      const int t = row0 + wr * 64 + mi * 16 + 4 * g + reg;
#pragma unroll
      for (int ni = 0; ni < 4; ++ni) {
        const int n = col0 + wc * 64 + ni * 16 + r16;
        if (MODE == 0) {
          const int b = t >> 11, l = t & (L_SEQ - 1);
          const int h = n >> 6, d = n & 63;
          ((short*)Cp)[(((size_t)(b * NH + h)) * L_SEQ + l) * HD + d] =
              f2bf(acc[mi][ni][reg] * scale);
        } else {
          ((float*)Cp)[(size_t)t * DIMN + n] = acc[mi][ni][reg];
        }
      }
    }
  }
}

// ---------------------------------------------------------------------------
// Flash attention, swapped-operand, exp2-domain fixed-max softmax.
// Round-7: 32 queries per wave (two 16-q B-blocks) -> every K/V A-frag LDS
// read feeds 2 MFMAs: 20 LDS reads per 32 MFMAs (was 18 per 16).
// Block = 4 waves = 128-q tile. Grid (L/128, B*H) = 512 blocks, 2/CU.
// LDS: kv 32KB + Ps 16KB = 48KB. Math identical to round 6.
// ---------------------------------------------------------------------------
__global__ __launch_bounds__(256) void attn_k(const short* __restrict__ Q,
                                              const short* __restrict__ K,
                                              const short* __restrict__ Vt,
                                              short* __restrict__ O) {
  __shared__ char kv[2][16384];                   // [buf][ K 8KB | Vt 8KB ]
  __shared__ __align__(16) short Ps[4][32][64];   // per-wave P (2 q-blocks), swizzled

  const int tid  = threadIdx.x;
  const int wave = tid >> 6, lane = tid & 63;
  const int g = lane >> 4, r16 = lane & 15;
  const int bh = blockIdx.y, qtile = blockIdx.x;
  const int qbase = qtile * 128 + wave * 32;
  const int dtile = qtile * 2 + (wave >> 1);      // the K-tile containing this wave's diagonal

  const short* Qh  = Q  + (size_t)bh * L_SEQ * HD;
  const short* Kh  = K  + (size_t)bh * L_SEQ * HD;
  const short* Vth = Vt + (size_t)bh * HD * L_SEQ;   // [d][l]

  // Q as B-fragments, two q-blocks: qb0 -> rows qbase+r16, qb1 -> +16
  bf16x8 bq[2][2];
  bq[0][0] = *(const bf16x8*)(Qh + (size_t)(qbase + r16) * HD + 8 * g);
  bq[0][1] = *(const bf16x8*)(Qh + (size_t)(qbase + r16) * HD + 8 * g + 32);
  bq[1][0] = *(const bf16x8*)(Qh + (size_t)(qbase + 16 + r16) * HD + 8 * g);
  bq[1][1] = *(const bf16x8*)(Qh + (size_t)(qbase + 16 + r16) * HD + 8 * g + 32);

  float lsum[2] = {0.f, 0.f};
  f32x4 o[2][4];
#pragma unroll
  for (int qb = 0; qb < 2; ++qb)
#pragma unroll
    for (int db = 0; db < 4; ++db) o[qb][db] = (f32x4){0.f, 0.f, 0.f, 0.f};

  // ---- precomputed per-lane invariants ----
  const int sw = r16 & 7;
  char* PsRow = (char*)Ps + wave * 4096 + r16 * 128;   // qb0 row; qb1 = +2048
  char* pw_addr[4];
#pragma unroll
  for (int kb = 0; kb < 4; ++kb) {
    const int gi = (2 * kb + (g >> 1)) ^ sw;
    pw_addr[kb] = PsRow + gi * 16 + (g & 1) * 8;
  }
  const char* bp_addr[2] = { PsRow + ((0 + g) ^ sw) * 16,
                             PsRow + ((4 + g) ^ sw) * 16 };
  const int slk0 = ((0 + g) ^ sw) * 16;
  const int slk1 = ((4 + g) ^ sw) * 16;
  const int rbase = r16 * 128;

  // ---- strength-reduced staging pointers (advance per tile) ----
  const int si1 = 256 + tid;
  const int row0s = tid >> 3,  c0s = (((tid & 7) ^ (row0s & 7)) << 3);
  const int row1s = si1 >> 3,  c1s = (((si1 & 7) ^ (row1s & 7)) << 3);
  const short* kp0 = Kh + (size_t)row0s * HD + c0s;
  const short* kp1 = Kh + (size_t)row1s * HD + c1s;
  const short* vp0 = Vth + (size_t)row0s * L_SEQ + c0s;
  const short* vp1 = Vth + (size_t)row1s * L_SEQ + c1s;
  const int ldo0 = tid * 16, ldo1 = si1 * 16;

  auto stage = [&](int buf) {   // buf literal at call sites
    char* base = kv[buf];
    gload_lds16(kp0, base + ldo0);
    gload_lds16(kp1, base + ldo1);
    gload_lds16(vp0, base + 8192 + ldo0);
    gload_lds16(vp1, base + 8192 + ldo1);
    kp0 += 64 * HD;
    kp1 += 64 * HD;
    vp0 += 64;
    vp1 += 64;
  };

  auto compute = [&](int buf, int kt) {   // buf literal at call sites
    const char* Kb = kv[buf];
    const char* Vb = kv[buf] + 8192;

    // --- QK^T (swapped): s[qb][kb] = S^T[key=kb*16+4g+reg][q = qbase+qb*16+r16]
    f32x4 s[2][4];
#pragma unroll
    for (int qb = 0; qb < 2; ++qb)
#pragma unroll
      for (int kb = 0; kb < 4; ++kb) s[qb][kb] = (f32x4){0.f, 0.f, 0.f, 0.f};
    __builtin_amdgcn_s_setprio(1);
#pragma unroll
    for (int kb = 0; kb < 4; ++kb) {
      bf16x8 ak0 = *(const bf16x8*)(Kb + rbase + kb * 2048 + slk0);
      s[0][kb] = __builtin_amdgcn_mfma_f32_16x16x32_bf16(ak0, bq[0][0], s[0][kb], 0, 0, 0);
      s[1][kb] = __builtin_amdgcn_mfma_f32_16x16x32_bf16(ak0, bq[1][0], s[1][kb], 0, 0, 0);
      bf16x8 ak1 = *(const bf16x8*)(Kb + rbase + kb * 2048 + slk1);
      s[0][kb] = __builtin_amdgcn_mfma_f32_16x16x32_bf16(ak1, bq[0][1], s[0][kb], 0, 0, 0);
      s[1][kb] = __builtin_amdgcn_mfma_f32_16x16x32_bf16(ak1, bq[1][1], s[1][kb], 0, 0, 0);
    }
    __builtin_amdgcn_s_setprio(0);

    // --- diagonal mask (one tile per wave; kt == dtile is wave-uniform)
    if (kt == dtile) {
#pragma unroll
      for (int qb = 0; qb < 2; ++qb) {
        const int qg = qbase + qb * 16 + r16;
#pragma unroll
        for (int kb = 0; kb < 4; ++kb)
#pragma unroll
          for (int r = 0; r < 4; ++r)
            if (kt * 64 + kb * 16 + 4 * g + r == qg) s[qb][kb][r] = -INFINITY;
      }
    }

    // --- fixed-max softmax: P = exp2(s); lane-local l accumulation
#pragma unroll
    for (int qb = 0; qb < 2; ++qb) {
#pragma unroll
      for (int kb = 0; kb < 4; ++kb)
#pragma unroll
        for (int r = 0; r < 4; ++r) s[qb][kb][r] = exp2f(s[qb][kb][r]);
      float t0 = (s[qb][0][0] + s[qb][0][1]) + (s[qb][0][2] + s[qb][0][3]);
      float t1 = (s[qb][1][0] + s[qb][1][1]) + (s[qb][1][2] + s[qb][1][3]);
      float t2 = (s[qb][2][0] + s[qb][2][1]) + (s[qb][2][2] + s[qb][2][3]);
      float t3 = (s[qb][3][0] + s[qb][3][1]) + (s[qb][3][2] + s[qb][3][3]);
      lsum[qb] += (t0 + t1) + (t2 + t3);
    }

    // --- P -> LDS: 2x cvt_pk + one 8B store per (qb, kb)
#pragma unroll
    for (int qb = 0; qb < 2; ++qb)
#pragma unroll
      for (int kb = 0; kb < 4; ++kb) {
        uint32x2 pw = { cvt_pk_bf16(s[qb][kb][0], s[qb][kb][1]),
                        cvt_pk_bf16(s[qb][kb][2], s[qb][kb][3]) };
        *(uint32x2*)(pw_addr[kb] + qb * 2048) = pw;
      }

    // --- PV (swapped): o[qb][db] = O^T[d=db*16+4g+reg][q]
    __builtin_amdgcn_s_setprio(1);
#pragma unroll
    for (int ks = 0; ks < 2; ++ks) {
      bf16x8 bp0 = *(const bf16x8*)bp_addr[ks];
      bf16x8 bp1 = *(const bf16x8*)(bp_addr[ks] + 2048);
      const int sl = ks ? slk1 : slk0;
#pragma unroll
      for (int db = 0; db < 4; ++db) {
        bf16x8 av = *(const bf16x8*)(Vb + rbase + db * 2048 + sl);
        o[0][db] = __builtin_amdgcn_mfma_f32_16x16x32_bf16(av, bp0, o[0][db], 0, 0, 0);
        o[1][db] = __builtin_amdgcn_mfma_f32_16x16x32_bf16(av, bp1, o[1][db], 0, 0, 0);
      }
    }
    __builtin_amdgcn_s_setprio(0);
  };

  stage(0);
  __syncthreads();

  for (int t = 0; t < L_SEQ / 64; t += 2) {
    stage(1);                      // tile t+1
    compute(0, t);
    __syncthreads();
    if (t + 2 < L_SEQ / 64) stage(0);   // tile t+2
    compute(1, t + 1);
    __syncthreads();
  }

  // cross-lane l reduce (q's keys live on lanes r16, r16+16, r16+32, r16+48)
#pragma unroll
  for (int qb = 0; qb < 2; ++qb) {
    lsum[qb] += __shfl_xor(lsum[qb], 16);
    lsum[qb] += __shfl_xor(lsum[qb], 32);
  }

  // epilogue: O^T[d][q] -> AO[token q][h*64+d], packed 8B stores
  const int b = bh >> 4, h = bh & 15;
#pragma unroll
  for (int qb = 0; qb < 2; ++qb) {
    const float inv = 1.0f / lsum[qb];
    const size_t rowO = (size_t)(b * L_SEQ + qbase + qb * 16 + r16) * DIMN + h * HD;
#pragma unroll
    for (int db = 0; db < 4; ++db) {
      uint32x2 ow = { cvt_pk_bf16(o[qb][db][0] * inv, o[qb][db][1] * inv),
                      cvt_pk_bf16(o[qb][db][2] * inv, o[qb][db][3] * inv) };
      *(uint32x2*)(O + rowO + db * 16 + 4 * g) = ow;
    }
  }
}

// ---------------------------------------------------------------------------
extern "C" void kernel_launch(void* const* d_in, const int* in_sizes, int n_in,
                              void* d_out, int out_size, void* d_ws, size_t ws_size,
                              hipStream_t stream) {
  const float* x  = (const float*)d_in[0];
  const float* Wq = (const float*)d_in[1];
  const float* Wk = (const float*)d_in[2];
  const float* Wv = (const float*)d_in[3];
  const float* Wo = (const float*)d_in[4];
  float* out = (float*)d_out;

  short* xb  = (short*)d_ws;
  short* Wqt = xb  + (size_t)NTOK * DIMN;
  short* Wkt = Wqt + (size_t)DIMN * DIMN;
  short* Wvt = Wkt + (size_t)DIMN * DIMN;
  short* Wot = Wvt + (size_t)DIMN * DIMN;
  short* Qb  = Wot + (size_t)DIMN * DIMN;
  short* Kb  = Qb  + (size_t)NTOK * DIMN;
  short* Vb  = Kb  + (size_t)NTOK * DIMN;
  short* Vtb = Vb  + (size_t)NTOK * DIMN;
  short* AO  = Vtb + (size_t)NTOK * DIMN;

  cast_x_k<<<NTOK * DIMN / (256 * 8), 256, 0, stream>>>(x, xb);
  const dim3 tgrid(DIMN / 64, DIMN / 64);
  castT_k<<<tgrid, 256, 0, stream>>>(Wq, Wqt);
  castT_k<<<tgrid, 256, 0, stream>>>(Wk, Wkt);
  castT_k<<<tgrid, 256, 0, stream>>>(Wv, Wvt);
  castT_k<<<tgrid, 256, 0, stream>>>(Wo, Wot);

  // QKV projections; Q pre-scaled by (1/sqrt(D)) * log2(e) for exp2 softmax
  mm_k<0><<<dim3(DIMN / 128, NTOK / 128, 3), 256, 0, stream>>>(
      xb, Wqt, Wkt, Wvt, Qb, Kb, Vb, 0.125f * 1.4426950408889634f);

  vT_k<<<dim3(L_SEQ / 64, NB * NH), 256, 0, stream>>>(Vb, Vtb);

  attn_k<<<dim3(L_SEQ / 128, NB * NH), 256, 0, stream>>>(Qb, Kb, Vtb, AO);

  mm_k<1><<<dim3(DIMN / 128, NTOK / 128, 1), 256, 0, stream>>>(
      AO, Wot, Wot, Wot, out, out, out, 1.0f);
}

// Round 8
// 140.170 us; speedup vs baseline: 1.0257x; 1.0257x over previous
//
#include <hip/hip_runtime.h>
#include <hip/hip_bf16.h>
#include <math.h>

#define L_SEQ 2048
#define DIMN  1024
#define NH    16
#define HD    64
#define NB    2
#define NTOK  (NB * L_SEQ)   // 4096

typedef __attribute__((ext_vector_type(8))) short bf16x8;
typedef __attribute__((ext_vector_type(4))) float f32x4;
typedef __attribute__((ext_vector_type(16))) float f32x16;
typedef __attribute__((ext_vector_type(4))) short short4v;
typedef __attribute__((ext_vector_type(2))) unsigned uint32x2;

__device__ __forceinline__ short f2bf(float x) {
  return (short)__bfloat16_as_ushort(__float2bfloat16(x));
}

// v_cvt_pk_bf16_f32: low16 = bf16(lo), high16 = bf16(hi)
__device__ __forceinline__ unsigned cvt_pk_bf16(float lo, float hi) {
  unsigned r;
  asm("v_cvt_pk_bf16_f32 %0, %1, %2" : "=v"(r) : "v"(lo), "v"(hi));
  return r;
}

// v_permlane32_swap_b32: a[32:63] <-> b[0:31]
__device__ __forceinline__ void permlane32_swap(unsigned& a, unsigned& b) {
  asm volatile("v_permlane32_swap_b32 %0, %1" : "+v"(a), "+v"(b));
}

__device__ __forceinline__ void gload_lds16(const short* gsrc, char* lds_dst) {
  __builtin_amdgcn_global_load_lds(
      (const __attribute__((address_space(1))) void*)gsrc,
      (__attribute__((address_space(3))) void*)lds_dst, 16, 0, 0);
}

// ---------------------------------------------------------------------------
// cast x fp32 -> bf16, 8 elems/thread
// ---------------------------------------------------------------------------
__global__ __launch_bounds__(256) void cast_x_k(const float* __restrict__ in,
                                                short* __restrict__ out) {
  const int i = (blockIdx.x * 256 + threadIdx.x) * 8;
  float4 a = *(const float4*)(in + i);
  float4 b = *(const float4*)(in + i + 4);
  bf16x8 o;
  o[0] = f2bf(a.x); o[1] = f2bf(a.y); o[2] = f2bf(a.z); o[3] = f2bf(a.w);
  o[4] = f2bf(b.x); o[5] = f2bf(b.y); o[6] = f2bf(b.z); o[7] = f2bf(b.w);
  *(bf16x8*)(out + i) = o;
}

// ---------------------------------------------------------------------------
// transpose+cast: Wt[n][k] = bf16(W[k][n]), 64x64 LDS tiles
// ---------------------------------------------------------------------------
__global__ __launch_bounds__(256) void castT_k(const float* __restrict__ W,
                                               short* __restrict__ Wt) {
  __shared__ float s[64][65];
  const int tid = threadIdx.x;
  const int k0 = blockIdx.y * 64, n0 = blockIdx.x * 64;
#pragma unroll
  for (int i = 0; i < 4; ++i) {
    int idx = i * 256 + tid;
    int r = idx >> 4, c = (idx & 15) * 4;
    float4 v = *(const float4*)(W + (size_t)(k0 + r) * DIMN + n0 + c);
    s[r][c] = v.x; s[r][c + 1] = v.y; s[r][c + 2] = v.z; s[r][c + 3] = v.w;
  }
  __syncthreads();
#pragma unroll
  for (int i = 0; i < 4; ++i) {
    int idx = i * 256 + tid;
    int r = idx >> 4, c = (idx & 15) * 4;
    short4v o = { f2bf(s[c][r]), f2bf(s[c + 1][r]), f2bf(s[c + 2][r]), f2bf(s[c + 3][r]) };
    *(short4v*)(Wt + (size_t)(n0 + r) * DIMN + k0 + c) = o;
  }
}

// ---------------------------------------------------------------------------
// transpose V: [B,H,L,D] bf16 -> Vt [B,H,D,L] bf16. Grid (L/64, B*H).
// ---------------------------------------------------------------------------
__global__ __launch_bounds__(256) void vT_k(const short* __restrict__ V,
                                            short* __restrict__ Vt) {
  __shared__ short s[64][72];
  const int tid = threadIdx.x;
  const int bh = blockIdx.y;
  const int l0 = blockIdx.x * 64;
  const int row = tid >> 2, c0 = (tid & 3) * 16;
  const short* Vh = V + (size_t)bh * L_SEQ * HD;
  bf16x8 a = *(const bf16x8*)(Vh + (size_t)(l0 + row) * HD + c0);
  bf16x8 b = *(const bf16x8*)(Vh + (size_t)(l0 + row) * HD + c0 + 8);
#pragma unroll
  for (int j = 0; j < 8; ++j) { s[c0 + j][row] = a[j]; s[c0 + 8 + j][row] = b[j]; }
  __syncthreads();
  short* Vth = Vt + (size_t)bh * HD * L_SEQ;
  bf16x8 o0 = *(const bf16x8*)&s[row][c0];
  bf16x8 o1 = *(const bf16x8*)&s[row][c0 + 8];
  *(bf16x8*)(Vth + (size_t)row * L_SEQ + l0 + c0) = o0;
  *(bf16x8*)(Vth + (size_t)row * L_SEQ + l0 + c0 + 8) = o1;
}

// ---------------------------------------------------------------------------
// bf16 MFMA GEMM. MODE 0: bf16 [B,H,L,D] out, scale0 on z==0 (Q).
// MODE 1: fp32 out row-major.
// ---------------------------------------------------------------------------
template <int MODE>
__global__ __launch_bounds__(256) void mm_k(const short* __restrict__ A,
                                            const short* __restrict__ B0,
                                            const short* __restrict__ B1,
                                            const short* __restrict__ B2,
                                            void* __restrict__ C0,
                                            void* __restrict__ C1,
                                            void* __restrict__ C2,
                                            float scale0) {
  __shared__ char smem[65536];
  const int tid  = threadIdx.x;
  const int lane = tid & 63, wv = tid >> 6;
  const int g = lane >> 4, r16 = lane & 15;
  const int wr = wv >> 1, wc = wv & 1;
  const int row0 = blockIdx.y * 128, col0 = blockIdx.x * 128;
  const int z = blockIdx.z;
  const short* Bt = (z == 0) ? B0 : (z == 1 ? B1 : B2);
  const float scale = (MODE == 0 && z == 0) ? scale0 : 1.0f;

  f32x4 acc[4][4];
#pragma unroll
  for (int mi = 0; mi < 4; ++mi)
#pragma unroll
    for (int ni = 0; ni < 4; ++ni) acc[mi][ni] = (f32x4){0.f, 0.f, 0.f, 0.f};

  auto stage = [&](int buf, int kt) {
    const int k0 = kt * 64;
    char* As = smem + buf * 32768;
    char* Bs = As + 16384;
#pragma unroll
    for (int j = 0; j < 4; ++j) {
      const int o = j * 4096 + wv * 1024 + lane * 16;
      const int row = o >> 7;
      const int slot = (o >> 4) & 7;
      const int ksrc = k0 + ((slot ^ (row & 7)) << 3);
      gload_lds16(A  + (size_t)(row0 + row) * DIMN + ksrc, As + j * 4096 + wv * 1024);
      gload_lds16(Bt + (size_t)(col0 + row) * DIMN + ksrc, Bs + j * 4096 + wv * 1024);
    }
  };

  auto compute = [&](int buf) {
    const char* As = smem + buf * 32768;
    const char* Bs = As + 16384;
#pragma unroll
    for (int ks = 0; ks < 2; ++ks) {
      bf16x8 a[4], b[4];
#pragma unroll
      for (int mi = 0; mi < 4; ++mi) {
        const int row = wr * 64 + mi * 16 + r16;
        const int slot = (ks * 4 + g) ^ (row & 7);
        a[mi] = *(const bf16x8*)(As + row * 128 + slot * 16);
      }
#pragma unroll
      for (int ni = 0; ni < 4; ++ni) {
        const int row = wc * 64 + ni * 16 + r16;
        const int slot = (ks * 4 + g) ^ (row & 7);
        b[ni] = *(const bf16x8*)(Bs + row * 128 + slot * 16);
      }
#pragma unroll
      for (int mi = 0; mi < 4; ++mi)
#pragma unroll
        for (int ni = 0; ni < 4; ++ni)
          acc[mi][ni] = __builtin_amdgcn_mfma_f32_16x16x32_bf16(a[mi], b[ni], acc[mi][ni], 0, 0, 0);
    }
  };

  stage(0, 0);
  __syncthreads();
  int cur = 0;
  for (int kt = 0; kt < DIMN / 64 - 1; ++kt) {
    stage(cur ^ 1, kt + 1);
    compute(cur);
    __syncthreads();
    cur ^= 1;
  }
  compute(cur);

  void* Cp = (z == 0) ? C0 : (z == 1 ? C1 : C2);
#pragma unroll
  for (int mi = 0; mi < 4; ++mi) {
#pragma unroll
    for (int reg = 0; reg < 4; ++reg) {
      const int t = row0 + wr * 64 + mi * 16 + 4 * g + reg;
#pragma unroll
      for (int ni = 0; ni < 4; ++ni) {
        const int n = col0 + wc * 64 + ni * 16 + r16;
        if (MODE == 0) {
          const int b = t >> 11, l = t & (L_SEQ - 1);
          const int h = n >> 6, d = n & 63;
          ((short*)Cp)[(((size_t)(b * NH + h)) * L_SEQ + l) * HD + d] =
              f2bf(acc[mi][ni][reg] * scale);
        } else {
          ((float*)Cp)[(size_t)t * DIMN + n] = acc[mi][ni][reg];
        }
      }
    }
  }
}

// ---------------------------------------------------------------------------
// Flash attention, 32x32x16 MFMA, swapped operands, fixed-max exp2 softmax,
// in-register P via cvt_pk + v_permlane32_swap (no P LDS).
//   S^T = mfma32(A=K, B=Q): lane(h=l>>5, r32=l&31) holds
//     S^T[key = 32kb + (reg&3)+8*(reg>>2)+4h][q = qbase + r32]
//   PV B-frag(kk): j0-3 & j4-7 assembled by swapping pack_lo/pack_hi with
//     the partner lane (l^32).
// Block = 4 waves x 32q = 128q. Grid (L/128, B*H) = 512 blocks.
// LDS = K/V double buffer only, 32 KB.
// ---------------------------------------------------------------------------
__global__ __launch_bounds__(256) void attn_k(const short* __restrict__ Q,
                                              const short* __restrict__ K,
                                              const short* __restrict__ Vt,
                                              short* __restrict__ O) {
  __shared__ char kv[2][16384];                   // [buf][ K 8KB | Vt 8KB ]

  const int tid  = threadIdx.x;
  const int wave = tid >> 6, lane = tid & 63;
  const int h = lane >> 5, r32 = lane & 31;
  const int bh = blockIdx.y, qtile = blockIdx.x;
  const int qbase = qtile * 128 + wave * 32;
  const int dtile = qtile * 2 + (wave >> 1);      // K-tile containing this wave's diagonal
  const int qg = qbase + r32;                     // this lane's query (both h halves)

  const short* Qh  = Q  + (size_t)bh * L_SEQ * HD;
  const short* Kh  = K  + (size_t)bh * L_SEQ * HD;
  const short* Vth = Vt + (size_t)bh * HD * L_SEQ;   // [d][l]

  // Q as B-fragments: qv[ks][j] = Q[qg][ks*16 + 8h + j]
  bf16x8 qv[4];
#pragma unroll
  for (int ks = 0; ks < 4; ++ks)
    qv[ks] = *(const bf16x8*)(Qh + (size_t)qg * HD + ks * 16 + 8 * h);

  float lsum = 0.f;
  f32x16 o32[2];
#pragma unroll
  for (int db = 0; db < 2; ++db)
#pragma unroll
    for (int r = 0; r < 16; ++r) o32[db][r] = 0.f;

  const int sw = r32 & 7;
  const int rbase = r32 * 128;

  // ---- strength-reduced staging pointers (advance per tile) ----
  const int si1 = 256 + tid;
  const int row0s = tid >> 3,  c0s = (((tid & 7) ^ (row0s & 7)) << 3);
  const int row1s = si1 >> 3,  c1s = (((si1 & 7) ^ (row1s & 7)) << 3);
  const short* kp0 = Kh + (size_t)row0s * HD + c0s;
  const short* kp1 = Kh + (size_t)row1s * HD + c1s;
  const short* vp0 = Vth + (size_t)row0s * L_SEQ + c0s;
  const short* vp1 = Vth + (size_t)row1s * L_SEQ + c1s;
  const int ldo0 = tid * 16, ldo1 = si1 * 16;

  auto stage = [&](int buf) {   // buf literal at call sites
    char* base = kv[buf];
    gload_lds16(kp0, base + ldo0);
    gload_lds16(kp1, base + ldo1);
    gload_lds16(vp0, base + 8192 + ldo0);
    gload_lds16(vp1, base + 8192 + ldo1);
    kp0 += 64 * HD;
    kp1 += 64 * HD;
    vp0 += 64;
    vp1 += 64;
  };

  auto compute = [&](int buf, int kt) {   // buf literal at call sites
    const char* Kb = kv[buf];
    const char* Vb = kv[buf] + 8192;

    // --- QK^T (swapped): 8 MFMA(32x32x16), 8 LDS reads
    f32x16 sa[2];
#pragma unroll
    for (int kb = 0; kb < 2; ++kb)
#pragma unroll
      for (int r = 0; r < 16; ++r) sa[kb][r] = 0.f;
    __builtin_amdgcn_s_setprio(1);
#pragma unroll
    for (int kb = 0; kb < 2; ++kb)
#pragma unroll
      for (int ks = 0; ks < 4; ++ks) {
        bf16x8 ak = *(const bf16x8*)(Kb + (kb * 32) * 128 + rbase + ((2 * ks + h) ^ sw) * 16);
        sa[kb] = __builtin_amdgcn_mfma_f32_32x32x16_bf16(ak, qv[ks], sa[kb], 0, 0, 0);
      }
    __builtin_amdgcn_s_setprio(0);

    // --- diagonal mask (only the wave's diagonal tile; wave-uniform branch)
    if (kt == dtile) {
      const int tgt = qg - kt * 64;   // in 0..63
#pragma unroll
      for (int kb = 0; kb < 2; ++kb)
#pragma unroll
        for (int r = 0; r < 16; ++r)
          if (kb * 32 + (r & 3) + 8 * (r >> 2) + 4 * h == tgt) sa[kb][r] = -INFINITY;
    }

    // --- fixed-max softmax: P = exp2(s); lane-local l accumulation
#pragma unroll
    for (int kb = 0; kb < 2; ++kb)
#pragma unroll
      for (int r = 0; r < 16; ++r) sa[kb][r] = exp2f(sa[kb][r]);
    float ps = 0.f;
#pragma unroll
    for (int kb = 0; kb < 2; ++kb) {
      float u0 = (sa[kb][0] + sa[kb][1]) + (sa[kb][2] + sa[kb][3]);
      float u1 = (sa[kb][4] + sa[kb][5]) + (sa[kb][6] + sa[kb][7]);
      float u2 = (sa[kb][8] + sa[kb][9]) + (sa[kb][10] + sa[kb][11]);
      float u3 = (sa[kb][12] + sa[kb][13]) + (sa[kb][14] + sa[kb][15]);
      ps += (u0 + u1) + (u2 + u3);
    }
    lsum += ps;

    // --- P -> PV B-frags in-register: per kk, pack own 8 values and swap
    //     halves with partner lane (l^32). frag words = [lo0, lo1, hi0, hi1].
    bf16x8 bp[4];
#pragma unroll
    for (int kk = 0; kk < 4; ++kk) {
      const int kb = kk >> 1, s8 = (kk & 1) * 8;
      unsigned lo0 = cvt_pk_bf16(sa[kb][s8 + 0], sa[kb][s8 + 1]);
      unsigned lo1 = cvt_pk_bf16(sa[kb][s8 + 2], sa[kb][s8 + 3]);
      unsigned hi0 = cvt_pk_bf16(sa[kb][s8 + 4], sa[kb][s8 + 5]);
      unsigned hi1 = cvt_pk_bf16(sa[kb][s8 + 6], sa[kb][s8 + 7]);
      permlane32_swap(lo0, hi0);
      permlane32_swap(lo1, hi1);
      union { unsigned w[4]; bf16x8 v; } u;
      u.w[0] = lo0; u.w[1] = lo1; u.w[2] = hi0; u.w[3] = hi1;
      bp[kk] = u.v;
    }

    // --- PV (swapped): 8 MFMA(32x32x16), 8 LDS reads
    __builtin_amdgcn_s_setprio(1);
#pragma unroll
    for (int kk = 0; kk < 4; ++kk)
#pragma unroll
      for (int db = 0; db < 2; ++db) {
        bf16x8 av = *(const bf16x8*)(Vb + (db * 32) * 128 + rbase + ((2 * kk + h) ^ sw) * 16);
        o32[db] = __builtin_amdgcn_mfma_f32_32x32x16_bf16(av, bp[kk], o32[db], 0, 0, 0);
      }
    __builtin_amdgcn_s_setprio(0);
  };

  stage(0);
  __syncthreads();

  for (int t = 0; t < L_SEQ / 64; t += 2) {
    stage(1);                      // tile t+1
    compute(0, t);
    __syncthreads();
    if (t + 2 < L_SEQ / 64) stage(0);   // tile t+2
    compute(1, t + 1);
    __syncthreads();
  }

  // q = qg lives on lanes l and l^32 (different key halves)
  lsum += __shfl_xor(lsum, 32);

  // epilogue: O^T[d][q] -> AO[token qg][h_head*64 + d], 8B packed stores
  const int b = bh >> 4, hh = bh & 15;
  const float inv = 1.0f / lsum;
  const size_t rowO = (size_t)(b * L_SEQ + qg) * DIMN + hh * HD;
#pragma unroll
  for (int db = 0; db < 2; ++db)
#pragma unroll
    for (int grp = 0; grp < 4; ++grp) {
      const int d0 = db * 32 + grp * 8 + 4 * h;
      uint32x2 ow = { cvt_pk_bf16(o32[db][grp * 4 + 0] * inv, o32[db][grp * 4 + 1] * inv),
                      cvt_pk_bf16(o32[db][grp * 4 + 2] * inv, o32[db][grp * 4 + 3] * inv) };
      *(uint32x2*)(O + rowO + d0) = ow;
    }
}

// ---------------------------------------------------------------------------
extern "C" void kernel_launch(void* const* d_in, const int* in_sizes, int n_in,
                              void* d_out, int out_size, void* d_ws, size_t ws_size,
                              hipStream_t stream) {
  const float* x  = (const float*)d_in[0];
  const float* Wq = (const float*)d_in[1];
  const float* Wk = (const float*)d_in[2];
  const float* Wv = (const float*)d_in[3];
  const float* Wo = (const float*)d_in[4];
  float* out = (float*)d_out;

  short* xb  = (short*)d_ws;
  short* Wqt = xb  + (size_t)NTOK * DIMN;
  short* Wkt = Wqt + (size_t)DIMN * DIMN;
  short* Wvt = Wkt + (size_t)DIMN * DIMN;
  short* Wot = Wvt + (size_t)DIMN * DIMN;
  short* Qb  = Wot + (size_t)DIMN * DIMN;
  short* Kb  = Qb  + (size_t)NTOK * DIMN;
  short* Vb  = Kb  + (size_t)NTOK * DIMN;
  short* Vtb = Vb  + (size_t)NTOK * DIMN;
  short* AO  = Vtb + (size_t)NTOK * DIMN;

  cast_x_k<<<NTOK * DIMN / (256 * 8), 256, 0, stream>>>(x, xb);
  const dim3 tgrid(DIMN / 64, DIMN / 64);
  castT_k<<<tgrid, 256, 0, stream>>>(Wq, Wqt);
  castT_k<<<tgrid, 256, 0, stream>>>(Wk, Wkt);
  castT_k<<<tgrid, 256, 0, stream>>>(Wv, Wvt);
  castT_k<<<tgrid, 256, 0, stream>>>(Wo, Wot);

  // QKV projections; Q pre-scaled by (1/sqrt(D)) * log2(e) for exp2 softmax
  mm_k<0><<<dim3(DIMN / 128, NTOK / 128, 3), 256, 0, stream>>>(
      xb, Wqt, Wkt, Wvt, Qb, Kb, Vb, 0.125f * 1.4426950408889634f);

  vT_k<<<dim3(L_SEQ / 64, NB * NH), 256, 0, stream>>>(Vb, Vtb);

  attn_k<<<dim3(L_SEQ / 128, NB * NH), 256, 0, stream>>>(Qb, Kb, Vtb, AO);

  mm_k<1><<<dim3(DIMN / 128, NTOK / 128, 1), 256, 0, stream>>>(
      AO, Wot, Wot, Wot, out, out, out, 1.0f);
}

// Round 9
// 138.579 us; speedup vs baseline: 1.0375x; 1.0115x over previous
//
#include <hip/hip_runtime.h>
#include <hip/hip_bf16.h>
#include <math.h>

#define L_SEQ 2048
#define DIMN  1024
#define NH    16
#define HD    64
#define NB    2
#define NTOK  (NB * L_SEQ)   // 4096

typedef __attribute__((ext_vector_type(8))) short bf16x8;
typedef __attribute__((ext_vector_type(4))) float f32x4;
typedef __attribute__((ext_vector_type(16))) float f32x16;
typedef __attribute__((ext_vector_type(4))) short short4v;
typedef __attribute__((ext_vector_type(2))) unsigned uint32x2;

__device__ __forceinline__ short f2bf(float x) {
  return (short)__bfloat16_as_ushort(__float2bfloat16(x));
}

// v_cvt_pk_bf16_f32: low16 = bf16(lo), high16 = bf16(hi)
__device__ __forceinline__ unsigned cvt_pk_bf16(float lo, float hi) {
  unsigned r;
  asm("v_cvt_pk_bf16_f32 %0, %1, %2" : "=v"(r) : "v"(lo), "v"(hi));
  return r;
}

// v_permlane32_swap_b32: a[32:63] <-> b[0:31]
__device__ __forceinline__ void permlane32_swap(unsigned& a, unsigned& b) {
  asm volatile("v_permlane32_swap_b32 %0, %1" : "+v"(a), "+v"(b));
}

__device__ __forceinline__ void gload_lds16(const short* gsrc, char* lds_dst) {
  __builtin_amdgcn_global_load_lds(
      (const __attribute__((address_space(1))) void*)gsrc,
      (__attribute__((address_space(3))) void*)lds_dst, 16, 0, 0);
}

// ---------------------------------------------------------------------------
// cast x fp32 -> bf16, 8 elems/thread
// ---------------------------------------------------------------------------
__global__ __launch_bounds__(256) void cast_x_k(const float* __restrict__ in,
                                                short* __restrict__ out) {
  const int i = (blockIdx.x * 256 + threadIdx.x) * 8;
  float4 a = *(const float4*)(in + i);
  float4 b = *(const float4*)(in + i + 4);
  bf16x8 o;
  o[0] = f2bf(a.x); o[1] = f2bf(a.y); o[2] = f2bf(a.z); o[3] = f2bf(a.w);
  o[4] = f2bf(b.x); o[5] = f2bf(b.y); o[6] = f2bf(b.z); o[7] = f2bf(b.w);
  *(bf16x8*)(out + i) = o;
}

// ---------------------------------------------------------------------------
// transpose+cast: Wt[n][k] = bf16(W[k][n]), 64x64 LDS tiles
// ---------------------------------------------------------------------------
__global__ __launch_bounds__(256) void castT_k(const float* __restrict__ W,
                                               short* __restrict__ Wt) {
  __shared__ float s[64][65];
  const int tid = threadIdx.x;
  const int k0 = blockIdx.y * 64, n0 = blockIdx.x * 64;
#pragma unroll
  for (int i = 0; i < 4; ++i) {
    int idx = i * 256 + tid;
    int r = idx >> 4, c = (idx & 15) * 4;
    float4 v = *(const float4*)(W + (size_t)(k0 + r) * DIMN + n0 + c);
    s[r][c] = v.x; s[r][c + 1] = v.y; s[r][c + 2] = v.z; s[r][c + 3] = v.w;
  }
  __syncthreads();
#pragma unroll
  for (int i = 0; i < 4; ++i) {
    int idx = i * 256 + tid;
    int r = idx >> 4, c = (idx & 15) * 4;
    short4v o = { f2bf(s[c][r]), f2bf(s[c + 1][r]), f2bf(s[c + 2][r]), f2bf(s[c + 3][r]) };
    *(short4v*)(Wt + (size_t)(n0 + r) * DIMN + k0 + c) = o;
  }
}

// ---------------------------------------------------------------------------
// transpose V: [B,H,L,D] bf16 -> Vt [B,H,D,L] bf16. Grid (L/64, B*H).
// ---------------------------------------------------------------------------
__global__ __launch_bounds__(256) void vT_k(const short* __restrict__ V,
                                            short* __restrict__ Vt) {
  __shared__ short s[64][72];
  const int tid = threadIdx.x;
  const int bh = blockIdx.y;
  const int l0 = blockIdx.x * 64;
  const int row = tid >> 2, c0 = (tid & 3) * 16;
  const short* Vh = V + (size_t)bh * L_SEQ * HD;
  bf16x8 a = *(const bf16x8*)(Vh + (size_t)(l0 + row) * HD + c0);
  bf16x8 b = *(const bf16x8*)(Vh + (size_t)(l0 + row) * HD + c0 + 8);
#pragma unroll
  for (int j = 0; j < 8; ++j) { s[c0 + j][row] = a[j]; s[c0 + 8 + j][row] = b[j]; }
  __syncthreads();
  short* Vth = Vt + (size_t)bh * HD * L_SEQ;
  bf16x8 o0 = *(const bf16x8*)&s[row][c0];
  bf16x8 o1 = *(const bf16x8*)&s[row][c0 + 8];
  *(bf16x8*)(Vth + (size_t)row * L_SEQ + l0 + c0) = o0;
  *(bf16x8*)(Vth + (size_t)row * L_SEQ + l0 + c0 + 8) = o1;
}

// ---------------------------------------------------------------------------
// bf16 MFMA GEMM. MODE 0: bf16 [B,H,L,D] out, scale0 on z==0 (Q).
// MODE 1: fp32 out row-major.
// ---------------------------------------------------------------------------
template <int MODE>
__global__ __launch_bounds__(256) void mm_k(const short* __restrict__ A,
                                            const short* __restrict__ B0,
                                            const short* __restrict__ B1,
                                            const short* __restrict__ B2,
                                            void* __restrict__ C0,
                                            void* __restrict__ C1,
                                            void* __restrict__ C2,
                                            float scale0) {
  __shared__ char smem[65536];
  const int tid  = threadIdx.x;
  const int lane = tid & 63, wv = tid >> 6;
  const int g = lane >> 4, r16 = lane & 15;
  const int wr = wv >> 1, wc = wv & 1;
  const int row0 = blockIdx.y * 128, col0 = blockIdx.x * 128;
  const int z = blockIdx.z;
  const short* Bt = (z == 0) ? B0 : (z == 1 ? B1 : B2);
  const float scale = (MODE == 0 && z == 0) ? scale0 : 1.0f;

  f32x4 acc[4][4];
#pragma unroll
  for (int mi = 0; mi < 4; ++mi)
#pragma unroll
    for (int ni = 0; ni < 4; ++ni) acc[mi][ni] = (f32x4){0.f, 0.f, 0.f, 0.f};

  auto stage = [&](int buf, int kt) {
    const int k0 = kt * 64;
    char* As = smem + buf * 32768;
    char* Bs = As + 16384;
#pragma unroll
    for (int j = 0; j < 4; ++j) {
      const int o = j * 4096 + wv * 1024 + lane * 16;
      const int row = o >> 7;
      const int slot = (o >> 4) & 7;
      const int ksrc = k0 + ((slot ^ (row & 7)) << 3);
      gload_lds16(A  + (size_t)(row0 + row) * DIMN + ksrc, As + j * 4096 + wv * 1024);
      gload_lds16(Bt + (size_t)(col0 + row) * DIMN + ksrc, Bs + j * 4096 + wv * 1024);
    }
  };

  auto compute = [&](int buf) {
    const char* As = smem + buf * 32768;
    const char* Bs = As + 16384;
#pragma unroll
    for (int ks = 0; ks < 2; ++ks) {
      bf16x8 a[4], b[4];
#pragma unroll
      for (int mi = 0; mi < 4; ++mi) {
        const int row = wr * 64 + mi * 16 + r16;
        const int slot = (ks * 4 + g) ^ (row & 7);
        a[mi] = *(const bf16x8*)(As + row * 128 + slot * 16);
      }
#pragma unroll
      for (int ni = 0; ni < 4; ++ni) {
        const int row = wc * 64 + ni * 16 + r16;
        const int slot = (ks * 4 + g) ^ (row & 7);
        b[ni] = *(const bf16x8*)(Bs + row * 128 + slot * 16);
      }
#pragma unroll
      for (int mi = 0; mi < 4; ++mi)
#pragma unroll
        for (int ni = 0; ni < 4; ++ni)
          acc[mi][ni] = __builtin_amdgcn_mfma_f32_16x16x32_bf16(a[mi], b[ni], acc[mi][ni], 0, 0, 0);
    }
  };

  stage(0, 0);
  __syncthreads();
  int cur = 0;
  for (int kt = 0; kt < DIMN / 64 - 1; ++kt) {
    stage(cur ^ 1, kt + 1);
    compute(cur);
    __syncthreads();
    cur ^= 1;
  }
  compute(cur);

  void* Cp = (z == 0) ? C0 : (z == 1 ? C1 : C2);
#pragma unroll
  for (int mi = 0; mi < 4; ++mi) {
#pragma unroll
    for (int reg = 0; reg < 4; ++reg) {
      const int t = row0 + wr * 64 + mi * 16 + 4 * g + reg;
#pragma unroll
      for (int ni = 0; ni < 4; ++ni) {
        const int n = col0 + wc * 64 + ni * 16 + r16;
        if (MODE == 0) {
          const int b = t >> 11, l = t & (L_SEQ - 1);
          const int h = n >> 6, d = n & 63;
          ((short*)Cp)[(((size_t)(b * NH + h)) * L_SEQ + l) * HD + d] =
              f2bf(acc[mi][ni][reg] * scale);
        } else {
          ((float*)Cp)[(size_t)t * DIMN + n] = acc[mi][ni][reg];
        }
      }
    }
  }
}

// ---------------------------------------------------------------------------
// Flash attention, 32x32x16 MFMA, swapped operands, fixed-max exp2 softmax,
// in-register P via cvt_pk + v_permlane32_swap.
// Round-9: (1) 3-buffer depth-2 pipeline with COUNTED vmcnt(4) + raw
// s_barrier (loads span 2 tile-periods; never drain to 0 in the loop);
// (2) XCD-bijective block remap: all 16 q-blocks of a head share an XCD
// (same id mod 8) -> per-XCD K/V working set 2 MB, L2-resident.
// Compute body byte-identical to round 8 (validated).
// ---------------------------------------------------------------------------
__global__ __launch_bounds__(256) void attn_k(const short* __restrict__ Q,
                                              const short* __restrict__ K,
                                              const short* __restrict__ Vt,
                                              short* __restrict__ O) {
  __shared__ char kv[3][16384];                   // [buf][ K 8KB | Vt 8KB ]

  const int tid  = threadIdx.x;
  const int wave = tid >> 6, lane = tid & 63;
  const int h = lane >> 5, r32 = lane & 31;

  // XCD-bijective remap: id = bx + 16*by; same-head blocks == same (id mod 8)
  const int id = blockIdx.x + 16 * blockIdx.y;    // 0..511
  const int bh = (id & 7) * 4 + (id >> 7);        // head, 4 heads per XCD
  const int qtile = (id >> 3) & 15;

  const int qbase = qtile * 128 + wave * 32;
  const int dtile = qtile * 2 + (wave >> 1);      // K-tile containing this wave's diagonal
  const int qg = qbase + r32;                     // this lane's query (both h halves)

  const short* Qh  = Q  + (size_t)bh * L_SEQ * HD;
  const short* Kh  = K  + (size_t)bh * L_SEQ * HD;
  const short* Vth = Vt + (size_t)bh * HD * L_SEQ;   // [d][l]

  // Q as B-fragments: qv[ks][j] = Q[qg][ks*16 + 8h + j]
  bf16x8 qv[4];
#pragma unroll
  for (int ks = 0; ks < 4; ++ks)
    qv[ks] = *(const bf16x8*)(Qh + (size_t)qg * HD + ks * 16 + 8 * h);

  float lsum = 0.f;
  f32x16 o32[2];
#pragma unroll
  for (int db = 0; db < 2; ++db)
#pragma unroll
    for (int r = 0; r < 16; ++r) o32[db][r] = 0.f;

  const int sw = r32 & 7;
  const int rbase = r32 * 128;

  // ---- strength-reduced staging pointers (advance per stage call) ----
  const int si1 = 256 + tid;
  const int row0s = tid >> 3,  c0s = (((tid & 7) ^ (row0s & 7)) << 3);
  const int row1s = si1 >> 3,  c1s = (((si1 & 7) ^ (row1s & 7)) << 3);
  const short* kp0 = Kh + (size_t)row0s * HD + c0s;
  const short* kp1 = Kh + (size_t)row1s * HD + c1s;
  const short* vp0 = Vth + (size_t)row0s * L_SEQ + c0s;
  const short* vp1 = Vth + (size_t)row1s * L_SEQ + c1s;
  const int ldo0 = tid * 16, ldo1 = si1 * 16;

  auto stage = [&](char* base) {
    gload_lds16(kp0, base + ldo0);
    gload_lds16(kp1, base + ldo1);
    gload_lds16(vp0, base + 8192 + ldo0);
    gload_lds16(vp1, base + 8192 + ldo1);
    kp0 += 64 * HD;
    kp1 += 64 * HD;
    vp0 += 64;
    vp1 += 64;
  };

  auto compute = [&](const char* Kb, int kt) {
    const char* Vb = Kb + 8192;

    // --- QK^T (swapped): 8 MFMA(32x32x16), 8 LDS reads
    f32x16 sa[2];
#pragma unroll
    for (int kb = 0; kb < 2; ++kb)
#pragma unroll
      for (int r = 0; r < 16; ++r) sa[kb][r] = 0.f;
    __builtin_amdgcn_s_setprio(1);
#pragma unroll
    for (int kb = 0; kb < 2; ++kb)
#pragma unroll
      for (int ks = 0; ks < 4; ++ks) {
        bf16x8 ak = *(const bf16x8*)(Kb + (kb * 32) * 128 + rbase + ((2 * ks + h) ^ sw) * 16);
        sa[kb] = __builtin_amdgcn_mfma_f32_32x32x16_bf16(ak, qv[ks], sa[kb], 0, 0, 0);
      }
    __builtin_amdgcn_s_setprio(0);

    // --- diagonal mask (only the wave's diagonal tile; wave-uniform branch)
    if (kt == dtile) {
      const int tgt = qg - kt * 64;   // in 0..63
#pragma unroll
      for (int kb = 0; kb < 2; ++kb)
#pragma unroll
        for (int r = 0; r < 16; ++r)
          if (kb * 32 + (r & 3) + 8 * (r >> 2) + 4 * h == tgt) sa[kb][r] = -INFINITY;
    }

    // --- fixed-max softmax: P = exp2(s); lane-local l accumulation
#pragma unroll
    for (int kb = 0; kb < 2; ++kb)
#pragma unroll
      for (int r = 0; r < 16; ++r) sa[kb][r] = exp2f(sa[kb][r]);
    float ps = 0.f;
#pragma unroll
    for (int kb = 0; kb < 2; ++kb) {
      float u0 = (sa[kb][0] + sa[kb][1]) + (sa[kb][2] + sa[kb][3]);
      float u1 = (sa[kb][4] + sa[kb][5]) + (sa[kb][6] + sa[kb][7]);
      float u2 = (sa[kb][8] + sa[kb][9]) + (sa[kb][10] + sa[kb][11]);
      float u3 = (sa[kb][12] + sa[kb][13]) + (sa[kb][14] + sa[kb][15]);
      ps += (u0 + u1) + (u2 + u3);
    }
    lsum += ps;

    // --- P -> PV B-frags in-register: per kk, pack own 8 values and swap
    //     halves with partner lane (l^32). frag words = [lo0, lo1, hi0, hi1].
    bf16x8 bp[4];
#pragma unroll
    for (int kk = 0; kk < 4; ++kk) {
      const int kb = kk >> 1, s8 = (kk & 1) * 8;
      unsigned lo0 = cvt_pk_bf16(sa[kb][s8 + 0], sa[kb][s8 + 1]);
      unsigned lo1 = cvt_pk_bf16(sa[kb][s8 + 2], sa[kb][s8 + 3]);
      unsigned hi0 = cvt_pk_bf16(sa[kb][s8 + 4], sa[kb][s8 + 5]);
      unsigned hi1 = cvt_pk_bf16(sa[kb][s8 + 6], sa[kb][s8 + 7]);
      permlane32_swap(lo0, hi0);
      permlane32_swap(lo1, hi1);
      union { unsigned w[4]; bf16x8 v; } u;
      u.w[0] = lo0; u.w[1] = lo1; u.w[2] = hi0; u.w[3] = hi1;
      bp[kk] = u.v;
    }

    // --- PV (swapped): 8 MFMA(32x32x16), 8 LDS reads
    __builtin_amdgcn_s_setprio(1);
#pragma unroll
    for (int kk = 0; kk < 4; ++kk)
#pragma unroll
      for (int db = 0; db < 2; ++db) {
        bf16x8 av = *(const bf16x8*)(Vb + (db * 32) * 128 + rbase + ((2 * kk + h) ^ sw) * 16);
        o32[db] = __builtin_amdgcn_mfma_f32_32x32x16_bf16(av, bp[kk], o32[db], 0, 0, 0);
      }
    __builtin_amdgcn_s_setprio(0);
  };

  // one pipeline step: counted-vmcnt wait + raw barrier, then stage + compute.
  // Every wave waits vmcnt BEFORE the barrier => after the barrier, all
  // waves' tile-t loads have landed. compute(t)'s ds_reads are all consumed
  // by its own MFMAs before this wave reaches the NEXT barrier, so the
  // stage that overwrites this buffer (2 iters later, after that barrier)
  // cannot race them.
  auto step = [&](const char* cbuf, char* sbuf, int t, bool dostage, bool last) {
    if (last) asm volatile("s_waitcnt vmcnt(0)" ::: "memory");
    else      asm volatile("s_waitcnt vmcnt(4)" ::: "memory");
    __builtin_amdgcn_s_barrier();
    __builtin_amdgcn_sched_barrier(0);
    if (dostage) stage(sbuf);
    compute(cbuf, t);
  };

  stage(kv[0]);   // tile 0
  stage(kv[1]);   // tile 1

  for (int t = 0; t < 30; t += 3) {
    step(kv[0], kv[2], t,     true, false);   // compute t,   stage t+2
    step(kv[1], kv[0], t + 1, true, false);   // compute t+1, stage t+3
    step(kv[2], kv[1], t + 2, true, false);   // compute t+2, stage t+4
  }
  step(kv[0], nullptr, 30, false, false);     // wait vmcnt(4): t31 still flying
  step(kv[1], nullptr, 31, false, true);      // wait vmcnt(0)

  // q = qg lives on lanes l and l^32 (different key halves)
  lsum += __shfl_xor(lsum, 32);

  // epilogue: O^T[d][q] -> AO[token qg][h_head*64 + d], 8B packed stores
  const int b = bh >> 4, hh = bh & 15;
  const float inv = 1.0f / lsum;
  const size_t rowO = (size_t)(b * L_SEQ + qg) * DIMN + hh * HD;
#pragma unroll
  for (int db = 0; db < 2; ++db)
#pragma unroll
    for (int grp = 0; grp < 4; ++grp) {
      const int d0 = db * 32 + grp * 8 + 4 * h;
      uint32x2 ow = { cvt_pk_bf16(o32[db][grp * 4 + 0] * inv, o32[db][grp * 4 + 1] * inv),
                      cvt_pk_bf16(o32[db][grp * 4 + 2] * inv, o32[db][grp * 4 + 3] * inv) };
      *(uint32x2*)(O + rowO + d0) = ow;
    }
}

// ---------------------------------------------------------------------------
extern "C" void kernel_launch(void* const* d_in, const int* in_sizes, int n_in,
                              void* d_out, int out_size, void* d_ws, size_t ws_size,
                              hipStream_t stream) {
  const float* x  = (const float*)d_in[0];
  const float* Wq = (const float*)d_in[1];
  const float* Wk = (const float*)d_in[2];
  const float* Wv = (const float*)d_in[3];
  const float* Wo = (const float*)d_in[4];
  float* out = (float*)d_out;

  short* xb  = (short*)d_ws;
  short* Wqt = xb  + (size_t)NTOK * DIMN;
  short* Wkt = Wqt + (size_t)DIMN * DIMN;
  short* Wvt = Wkt + (size_t)DIMN * DIMN;
  short* Wot = Wvt + (size_t)DIMN * DIMN;
  short* Qb  = Wot + (size_t)DIMN * DIMN;
  short* Kb  = Qb  + (size_t)NTOK * DIMN;
  short* Vb  = Kb  + (size_t)NTOK * DIMN;
  short* Vtb = Vb  + (size_t)NTOK * DIMN;
  short* AO  = Vtb + (size_t)NTOK * DIMN;

  cast_x_k<<<NTOK * DIMN / (256 * 8), 256, 0, stream>>>(x, xb);
  const dim3 tgrid(DIMN / 64, DIMN / 64);
  castT_k<<<tgrid, 256, 0, stream>>>(Wq, Wqt);
  castT_k<<<tgrid, 256, 0, stream>>>(Wk, Wkt);
  castT_k<<<tgrid, 256, 0, stream>>>(Wv, Wvt);
  castT_k<<<tgrid, 256, 0, stream>>>(Wo, Wot);

  // QKV projections; Q pre-scaled by (1/sqrt(D)) * log2(e) for exp2 softmax
  mm_k<0><<<dim3(DIMN / 128, NTOK / 128, 3), 256, 0, stream>>>(
      xb, Wqt, Wkt, Wvt, Qb, Kb, Vb, 0.125f * 1.4426950408889634f);

  vT_k<<<dim3(L_SEQ / 64, NB * NH), 256, 0, stream>>>(Vb, Vtb);

  attn_k<<<dim3(L_SEQ / 128, NB * NH), 256, 0, stream>>>(Qb, Kb, Vtb, AO);

  mm_k<1><<<dim3(DIMN / 128, NTOK / 128, 1), 256, 0, stream>>>(
      AO, Wot, Wot, Wot, out, out, out, 1.0f);
}

// Round 10
// 131.778 us; speedup vs baseline: 1.0911x; 1.0516x over previous
//
#include <hip/hip_runtime.h>
#include <hip/hip_bf16.h>
#include <math.h>

#define L_SEQ 2048
#define DIMN  1024
#define NH    16
#define HD    64
#define NB    2
#define NTOK  (NB * L_SEQ)   // 4096

typedef __attribute__((ext_vector_type(8))) short bf16x8;
typedef __attribute__((ext_vector_type(4))) float f32x4;
typedef __attribute__((ext_vector_type(16))) float f32x16;
typedef __attribute__((ext_vector_type(4))) short short4v;
typedef __attribute__((ext_vector_type(2))) unsigned uint32x2;

__device__ __forceinline__ short f2bf(float x) {
  return (short)__bfloat16_as_ushort(__float2bfloat16(x));
}
__device__ __forceinline__ float bf2f(short x) {
  union { unsigned u; float f; } c;
  c.u = ((unsigned)(unsigned short)x) << 16;
  return c.f;
}

// v_cvt_pk_bf16_f32: low16 = bf16(lo), high16 = bf16(hi)
__device__ __forceinline__ unsigned cvt_pk_bf16(float lo, float hi) {
  unsigned r;
  asm("v_cvt_pk_bf16_f32 %0, %1, %2" : "=v"(r) : "v"(lo), "v"(hi));
  return r;
}

// v_permlane32_swap_b32: a[32:63] <-> b[0:31]
__device__ __forceinline__ void permlane32_swap(unsigned& a, unsigned& b) {
  asm volatile("v_permlane32_swap_b32 %0, %1" : "+v"(a), "+v"(b));
}

__device__ __forceinline__ void gload_lds16(const short* gsrc, char* lds_dst) {
  __builtin_amdgcn_global_load_lds(
      (const __attribute__((address_space(1))) void*)gsrc,
      (__attribute__((address_space(3))) void*)lds_dst, 16, 0, 0);
}

// ---------------------------------------------------------------------------
// cast x fp32 -> bf16, 8 elems/thread
// ---------------------------------------------------------------------------
__global__ __launch_bounds__(256) void cast_x_k(const float* __restrict__ in,
                                                short* __restrict__ out) {
  const int i = (blockIdx.x * 256 + threadIdx.x) * 8;
  float4 a = *(const float4*)(in + i);
  float4 b = *(const float4*)(in + i + 4);
  bf16x8 o;
  o[0] = f2bf(a.x); o[1] = f2bf(a.y); o[2] = f2bf(a.z); o[3] = f2bf(a.w);
  o[4] = f2bf(b.x); o[5] = f2bf(b.y); o[6] = f2bf(b.z); o[7] = f2bf(b.w);
  *(bf16x8*)(out + i) = o;
}

// ---------------------------------------------------------------------------
// transpose+cast: Wt[n][k] = bf16(W[k][n]), 64x64 LDS tiles
// ---------------------------------------------------------------------------
__global__ __launch_bounds__(256) void castT_k(const float* __restrict__ W,
                                               short* __restrict__ Wt) {
  __shared__ float s[64][65];
  const int tid = threadIdx.x;
  const int k0 = blockIdx.y * 64, n0 = blockIdx.x * 64;
#pragma unroll
  for (int i = 0; i < 4; ++i) {
    int idx = i * 256 + tid;
    int r = idx >> 4, c = (idx & 15) * 4;
    float4 v = *(const float4*)(W + (size_t)(k0 + r) * DIMN + n0 + c);
    s[r][c] = v.x; s[r][c + 1] = v.y; s[r][c + 2] = v.z; s[r][c + 3] = v.w;
  }
  __syncthreads();
#pragma unroll
  for (int i = 0; i < 4; ++i) {
    int idx = i * 256 + tid;
    int r = idx >> 4, c = (idx & 15) * 4;
    short4v o = { f2bf(s[c][r]), f2bf(s[c + 1][r]), f2bf(s[c + 2][r]), f2bf(s[c + 3][r]) };
    *(short4v*)(Wt + (size_t)(n0 + r) * DIMN + k0 + c) = o;
  }
}

// ---------------------------------------------------------------------------
// transpose V: [B,H,L,D] bf16 -> Vt [B,H,D,L] bf16. Grid (L/64, B*H).
// ---------------------------------------------------------------------------
__global__ __launch_bounds__(256) void vT_k(const short* __restrict__ V,
                                            short* __restrict__ Vt) {
  __shared__ short s[64][72];
  const int tid = threadIdx.x;
  const int bh = blockIdx.y;
  const int l0 = blockIdx.x * 64;
  const int row = tid >> 2, c0 = (tid & 3) * 16;
  const short* Vh = V + (size_t)bh * L_SEQ * HD;
  bf16x8 a = *(const bf16x8*)(Vh + (size_t)(l0 + row) * HD + c0);
  bf16x8 b = *(const bf16x8*)(Vh + (size_t)(l0 + row) * HD + c0 + 8);
#pragma unroll
  for (int j = 0; j < 8; ++j) { s[c0 + j][row] = a[j]; s[c0 + 8 + j][row] = b[j]; }
  __syncthreads();
  short* Vth = Vt + (size_t)bh * HD * L_SEQ;
  bf16x8 o0 = *(const bf16x8*)&s[row][c0];
  bf16x8 o1 = *(const bf16x8*)&s[row][c0 + 8];
  *(bf16x8*)(Vth + (size_t)row * L_SEQ + l0 + c0) = o0;
  *(bf16x8*)(Vth + (size_t)row * L_SEQ + l0 + c0 + 8) = o1;
}

// ---------------------------------------------------------------------------
// bf16 MFMA GEMM. MODE 0: bf16 [B,H,L,D] out, scale0 on z==0 (Q).
// MODE 1: fp32 out row-major.
// ---------------------------------------------------------------------------
template <int MODE>
__global__ __launch_bounds__(256) void mm_k(const short* __restrict__ A,
                                            const short* __restrict__ B0,
                                            const short* __restrict__ B1,
                                            const short* __restrict__ B2,
                                            void* __restrict__ C0,
                                            void* __restrict__ C1,
                                            void* __restrict__ C2,
                                            float scale0) {
  __shared__ char smem[65536];
  const int tid  = threadIdx.x;
  const int lane = tid & 63, wv = tid >> 6;
  const int g = lane >> 4, r16 = lane & 15;
  const int wr = wv >> 1, wc = wv & 1;
  const int row0 = blockIdx.y * 128, col0 = blockIdx.x * 128;
  const int z = blockIdx.z;
  const short* Bt = (z == 0) ? B0 : (z == 1 ? B1 : B2);
  const float scale = (MODE == 0 && z == 0) ? scale0 : 1.0f;

  f32x4 acc[4][4];
#pragma unroll
  for (int mi = 0; mi < 4; ++mi)
#pragma unroll
    for (int ni = 0; ni < 4; ++ni) acc[mi][ni] = (f32x4){0.f, 0.f, 0.f, 0.f};

  auto stage = [&](int buf, int kt) {
    const int k0 = kt * 64;
    char* As = smem + buf * 32768;
    char* Bs = As + 16384;
#pragma unroll
    for (int j = 0; j < 4; ++j) {
      const int o = j * 4096 + wv * 1024 + lane * 16;
      const int row = o >> 7;
      const int slot = (o >> 4) & 7;
      const int ksrc = k0 + ((slot ^ (row & 7)) << 3);
      gload_lds16(A  + (size_t)(row0 + row) * DIMN + ksrc, As + j * 4096 + wv * 1024);
      gload_lds16(Bt + (size_t)(col0 + row) * DIMN + ksrc, Bs + j * 4096 + wv * 1024);
    }
  };

  auto compute = [&](int buf) {
    const char* As = smem + buf * 32768;
    const char* Bs = As + 16384;
#pragma unroll
    for (int ks = 0; ks < 2; ++ks) {
      bf16x8 a[4], b[4];
#pragma unroll
      for (int mi = 0; mi < 4; ++mi) {
        const int row = wr * 64 + mi * 16 + r16;
        const int slot = (ks * 4 + g) ^ (row & 7);
        a[mi] = *(const bf16x8*)(As + row * 128 + slot * 16);
      }
#pragma unroll
      for (int ni = 0; ni < 4; ++ni) {
        const int row = wc * 64 + ni * 16 + r16;
        const int slot = (ks * 4 + g) ^ (row & 7);
        b[ni] = *(const bf16x8*)(Bs + row * 128 + slot * 16);
      }
#pragma unroll
      for (int mi = 0; mi < 4; ++mi)
#pragma unroll
        for (int ni = 0; ni < 4; ++ni)
          acc[mi][ni] = __builtin_amdgcn_mfma_f32_16x16x32_bf16(a[mi], b[ni], acc[mi][ni], 0, 0, 0);
    }
  };

  stage(0, 0);
  __syncthreads();
  int cur = 0;
  for (int kt = 0; kt < DIMN / 64 - 1; ++kt) {
    stage(cur ^ 1, kt + 1);
    compute(cur);
    __syncthreads();
    cur ^= 1;
  }
  compute(cur);

  void* Cp = (z == 0) ? C0 : (z == 1 ? C1 : C2);
#pragma unroll
  for (int mi = 0; mi < 4; ++mi) {
#pragma unroll
    for (int reg = 0; reg < 4; ++reg) {
      const int t = row0 + wr * 64 + mi * 16 + 4 * g + reg;
#pragma unroll
      for (int ni = 0; ni < 4; ++ni) {
        const int n = col0 + wc * 64 + ni * 16 + r16;
        if (MODE == 0) {
          const int b = t >> 11, l = t & (L_SEQ - 1);
          const int h = n >> 6, d = n & 63;
          ((short*)Cp)[(((size_t)(b * NH + h)) * L_SEQ + l) * HD + d] =
              f2bf(acc[mi][ni][reg] * scale);
        } else {
          ((float*)Cp)[(size_t)t * DIMN + n] = acc[mi][ni][reg];
        }
      }
    }
  }
}

// ---------------------------------------------------------------------------
// Flash attention, 32x32x16 MFMA, swapped operands, fixed-max exp2 softmax,
// in-register P via cvt_pk + v_permlane32_swap.
// Round-10: SPLIT-K x2 (fixed-max partials are additive: each block does
// 128q x 1024 keys, writes unnormalized bf16 O-partial + lsum; combine_k
// sums and normalizes). Grid 1024 -> 4 blocks/CU = 16 waves/CU (was 8).
// LDS: 2 buffers, 32KB. Raw v_exp_f32 via __builtin_amdgcn_exp2f.
// Compute body otherwise identical to round 8/9 (validated).
// ---------------------------------------------------------------------------
__global__ __launch_bounds__(256) void attn_k(const short* __restrict__ Q,
                                              const short* __restrict__ K,
                                              const short* __restrict__ Vt,
                                              short* __restrict__ Op0,
                                              short* __restrict__ Op1,
                                              float* __restrict__ Lp) {
  __shared__ char kv[2][16384];                   // [buf][ K 8KB | Vt 8KB ]

  const int tid  = threadIdx.x;
  const int wave = tid >> 6, lane = tid & 63;
  const int h = lane >> 5, r32 = lane & 31;

  // XCD-bijective remap over 1024 blocks: xcd = id&7 (same-head blocks share
  // an XCD); per XCD: 4 heads x (16 qtiles x 2 splits) = 128 blocks, 2MB K/V.
  const int id = blockIdx.x + 32 * blockIdx.y;    // 0..1023
  const int j8 = id >> 3;                         // 0..127
  const int bh = (id & 7) * 4 + (j8 >> 5);        // head
  const int qtile = (j8 >> 1) & 15;
  const int split = j8 & 1;

  const int qbase = qtile * 128 + wave * 32;
  const int dtile = qtile * 2 + (wave >> 1);      // global K-tile with this wave's diagonal
  const int qg = qbase + r32;                     // this lane's query (both h halves)
  const int kbase = split * 16;                   // this block's first global K-tile

  const short* Qh  = Q  + (size_t)bh * L_SEQ * HD;
  const short* Kh  = K  + (size_t)bh * L_SEQ * HD;
  const short* Vth = Vt + (size_t)bh * HD * L_SEQ;   // [d][l]

  // Q as B-fragments: qv[ks][j] = Q[qg][ks*16 + 8h + j]
  bf16x8 qv[4];
#pragma unroll
  for (int ks = 0; ks < 4; ++ks)
    qv[ks] = *(const bf16x8*)(Qh + (size_t)qg * HD + ks * 16 + 8 * h);

  float lsum = 0.f;
  f32x16 o32[2];
#pragma unroll
  for (int db = 0; db < 2; ++db)
#pragma unroll
    for (int r = 0; r < 16; ++r) o32[db][r] = 0.f;

  const int sw = r32 & 7;
  const int rbase = r32 * 128;

  // ---- strength-reduced staging pointers (advance per stage call) ----
  const int si1 = 256 + tid;
  const int row0s = tid >> 3,  c0s = (((tid & 7) ^ (row0s & 7)) << 3);
  const int row1s = si1 >> 3,  c1s = (((si1 & 7) ^ (row1s & 7)) << 3);
  const short* kp0 = Kh + (size_t)(split * 1024 + row0s) * HD + c0s;
  const short* kp1 = Kh + (size_t)(split * 1024 + row1s) * HD + c1s;
  const short* vp0 = Vth + (size_t)row0s * L_SEQ + split * 1024 + c0s;
  const short* vp1 = Vth + (size_t)row1s * L_SEQ + split * 1024 + c1s;
  const int ldo0 = tid * 16, ldo1 = si1 * 16;

  auto stage = [&](char* base) {
    gload_lds16(kp0, base + ldo0);
    gload_lds16(kp1, base + ldo1);
    gload_lds16(vp0, base + 8192 + ldo0);
    gload_lds16(vp1, base + 8192 + ldo1);
    kp0 += 64 * HD;
    kp1 += 64 * HD;
    vp0 += 64;
    vp1 += 64;
  };

  auto compute = [&](const char* Kb, int kt) {
    const char* Vb = Kb + 8192;

    // --- QK^T (swapped): 8 MFMA(32x32x16), 8 LDS reads
    f32x16 sa[2];
#pragma unroll
    for (int kb = 0; kb < 2; ++kb)
#pragma unroll
      for (int r = 0; r < 16; ++r) sa[kb][r] = 0.f;
    __builtin_amdgcn_s_setprio(1);
#pragma unroll
    for (int kb = 0; kb < 2; ++kb)
#pragma unroll
      for (int ks = 0; ks < 4; ++ks) {
        bf16x8 ak = *(const bf16x8*)(Kb + (kb * 32) * 128 + rbase + ((2 * ks + h) ^ sw) * 16);
        sa[kb] = __builtin_amdgcn_mfma_f32_32x32x16_bf16(ak, qv[ks], sa[kb], 0, 0, 0);
      }
    __builtin_amdgcn_s_setprio(0);

    // --- diagonal mask (only the wave's diagonal tile; wave-uniform branch)
    if (kt == dtile) {
      const int tgt = qg - kt * 64;   // in 0..63
#pragma unroll
      for (int kb = 0; kb < 2; ++kb)
#pragma unroll
        for (int r = 0; r < 16; ++r)
          if (kb * 32 + (r & 3) + 8 * (r >> 2) + 4 * h == tgt) sa[kb][r] = -INFINITY;
    }

    // --- fixed-max softmax: P = exp2(s) via raw v_exp_f32; lane-local l
#pragma unroll
    for (int kb = 0; kb < 2; ++kb)
#pragma unroll
      for (int r = 0; r < 16; ++r) sa[kb][r] = __builtin_amdgcn_exp2f(sa[kb][r]);
    float ps = 0.f;
#pragma unroll
    for (int kb = 0; kb < 2; ++kb) {
      float u0 = (sa[kb][0] + sa[kb][1]) + (sa[kb][2] + sa[kb][3]);
      float u1 = (sa[kb][4] + sa[kb][5]) + (sa[kb][6] + sa[kb][7]);
      float u2 = (sa[kb][8] + sa[kb][9]) + (sa[kb][10] + sa[kb][11]);
      float u3 = (sa[kb][12] + sa[kb][13]) + (sa[kb][14] + sa[kb][15]);
      ps += (u0 + u1) + (u2 + u3);
    }
    lsum += ps;

    // --- P -> PV B-frags in-register: cvt_pk + permlane32_swap
    bf16x8 bp[4];
#pragma unroll
    for (int kk = 0; kk < 4; ++kk) {
      const int kb = kk >> 1, s8 = (kk & 1) * 8;
      unsigned lo0 = cvt_pk_bf16(sa[kb][s8 + 0], sa[kb][s8 + 1]);
      unsigned lo1 = cvt_pk_bf16(sa[kb][s8 + 2], sa[kb][s8 + 3]);
      unsigned hi0 = cvt_pk_bf16(sa[kb][s8 + 4], sa[kb][s8 + 5]);
      unsigned hi1 = cvt_pk_bf16(sa[kb][s8 + 6], sa[kb][s8 + 7]);
      permlane32_swap(lo0, hi0);
      permlane32_swap(lo1, hi1);
      union { unsigned w[4]; bf16x8 v; } u;
      u.w[0] = lo0; u.w[1] = lo1; u.w[2] = hi0; u.w[3] = hi1;
      bp[kk] = u.v;
    }

    // --- PV (swapped): 8 MFMA(32x32x16), 8 LDS reads
    __builtin_amdgcn_s_setprio(1);
#pragma unroll
    for (int kk = 0; kk < 4; ++kk)
#pragma unroll
      for (int db = 0; db < 2; ++db) {
        bf16x8 av = *(const bf16x8*)(Vb + (db * 32) * 128 + rbase + ((2 * kk + h) ^ sw) * 16);
        o32[db] = __builtin_amdgcn_mfma_f32_32x32x16_bf16(av, bp[kk], o32[db], 0, 0, 0);
      }
    __builtin_amdgcn_s_setprio(0);
  };

  // 2-buffer rotation. Per iteration: vmcnt(0) (tile-t loads were issued a
  // full compute ago -> already landed, cheap) -> barrier (all waves' loads
  // visible) -> stage(t+1) (safe: overwrites buffer whose readers finished
  // before the barrier) -> compute(t).
#define STEP(CBUF, SBUF, KT, DO_STAGE)                        \
  do {                                                        \
    asm volatile("s_waitcnt vmcnt(0)" ::: "memory");          \
    __builtin_amdgcn_s_barrier();                             \
    __builtin_amdgcn_sched_barrier(0);                        \
    if (DO_STAGE) stage(SBUF);                                \
    compute(CBUF, KT);                                        \
  } while (0)

  stage(kv[0]);   // first tile
  for (int i = 0; i < 14; i += 2) {
    STEP(kv[0], kv[1], kbase + i,     true);
    STEP(kv[1], kv[0], kbase + i + 1, true);
  }
  STEP(kv[0], kv[1], kbase + 14, true);
  STEP(kv[1], kv[0], kbase + 15, false);
#undef STEP

  // q = qg lives on lanes l and l^32 (different key halves)
  lsum += __shfl_xor(lsum, 32);

  // epilogue: unnormalized partial O (bf16) + lsum
  short* Opart = split ? Op1 : Op0;
  const size_t rowO = ((size_t)bh * L_SEQ + qg) * HD;
#pragma unroll
  for (int db = 0; db < 2; ++db)
#pragma unroll
    for (int grp = 0; grp < 4; ++grp) {
      const int d0 = db * 32 + grp * 8 + 4 * h;
      uint32x2 ow = { cvt_pk_bf16(o32[db][grp * 4 + 0], o32[db][grp * 4 + 1]),
                      cvt_pk_bf16(o32[db][grp * 4 + 2], o32[db][grp * 4 + 3]) };
      *(uint32x2*)(Opart + rowO + d0) = ow;
    }
  if (h == 0)
    Lp[(size_t)(split * NB * NH + bh) * L_SEQ + qg] = lsum;
}

// ---------------------------------------------------------------------------
// combine: AO[b*L+q][h*64+d] = (Op0 + Op1) / (l0 + l1), bf16 out.
// One thread per (bh, q, 8 dims). Grid 2048 x 256.
// ---------------------------------------------------------------------------
__global__ __launch_bounds__(256) void combine_k(const short* __restrict__ Op0,
                                                 const short* __restrict__ Op1,
                                                 const float* __restrict__ Lp,
                                                 short* __restrict__ AO) {
  const int idx = blockIdx.x * 256 + threadIdx.x;   // 0..524287
  const int d8 = (idx & 7) * 8;
  const int q  = (idx >> 3) & (L_SEQ - 1);
  const int bh = idx >> 14;                         // 0..31
  const size_t po = ((size_t)bh * L_SEQ + q) * HD + d8;
  bf16x8 p0 = *(const bf16x8*)(Op0 + po);
  bf16x8 p1 = *(const bf16x8*)(Op1 + po);
  const float l0 = Lp[(size_t)bh * L_SEQ + q];
  const float l1 = Lp[(size_t)(NB * NH + bh) * L_SEQ + q];
  const float inv = 1.0f / (l0 + l1);
  const int b = bh >> 4, hh = bh & 15;
  bf16x8 o;
#pragma unroll
  for (int j = 0; j < 8; ++j)
    o[j] = f2bf((bf2f(p0[j]) + bf2f(p1[j])) * inv);
  *(bf16x8*)(AO + ((size_t)(b * L_SEQ + q)) * DIMN + hh * HD + d8) = o;
}

// ---------------------------------------------------------------------------
extern "C" void kernel_launch(void* const* d_in, const int* in_sizes, int n_in,
                              void* d_out, int out_size, void* d_ws, size_t ws_size,
                              hipStream_t stream) {
  const float* x  = (const float*)d_in[0];
  const float* Wq = (const float*)d_in[1];
  const float* Wk = (const float*)d_in[2];
  const float* Wv = (const float*)d_in[3];
  const float* Wo = (const float*)d_in[4];
  float* out = (float*)d_out;

  short* xb  = (short*)d_ws;
  short* Wqt = xb  + (size_t)NTOK * DIMN;
  short* Wkt = Wqt + (size_t)DIMN * DIMN;
  short* Wvt = Wkt + (size_t)DIMN * DIMN;
  short* Wot = Wvt + (size_t)DIMN * DIMN;
  short* Qb  = Wot + (size_t)DIMN * DIMN;
  short* Kb  = Qb  + (size_t)NTOK * DIMN;
  short* Vb  = Kb  + (size_t)NTOK * DIMN;
  short* Vtb = Vb  + (size_t)NTOK * DIMN;
  short* AO  = Vtb + (size_t)NTOK * DIMN;
  float* Lp  = (float*)(AO + (size_t)NTOK * DIMN);   // 2*32*2048 f32 = 512KB
  // partial-O buffers reuse dead regions: xb (dead after QKV proj),
  // Vb (dead after vT_k). Each 32*2048*64 bf16 = 8MB, exactly their size.
  short* Op0 = xb;
  short* Op1 = Vb;

  cast_x_k<<<NTOK * DIMN / (256 * 8), 256, 0, stream>>>(x, xb);
  const dim3 tgrid(DIMN / 64, DIMN / 64);
  castT_k<<<tgrid, 256, 0, stream>>>(Wq, Wqt);
  castT_k<<<tgrid, 256, 0, stream>>>(Wk, Wkt);
  castT_k<<<tgrid, 256, 0, stream>>>(Wv, Wvt);
  castT_k<<<tgrid, 256, 0, stream>>>(Wo, Wot);

  // QKV projections; Q pre-scaled by (1/sqrt(D)) * log2(e) for exp2 softmax
  mm_k<0><<<dim3(DIMN / 128, NTOK / 128, 3), 256, 0, stream>>>(
      xb, Wqt, Wkt, Wvt, Qb, Kb, Vb, 0.125f * 1.4426950408889634f);

  vT_k<<<dim3(L_SEQ / 64, NB * NH), 256, 0, stream>>>(Vb, Vtb);

  // split-K x2 flash attention -> bf16 partials + lsums
  attn_k<<<dim3(32, NB * NH), 256, 0, stream>>>(Qb, Kb, Vtb, Op0, Op1, Lp);

  combine_k<<<2048, 256, 0, stream>>>(Op0, Op1, Lp, AO);

  mm_k<1><<<dim3(DIMN / 128, NTOK / 128, 1), 256, 0, stream>>>(
      AO, Wot, Wot, Wot, out, out, out, 1.0f);
}